// Round 5
// baseline (233.724 us; speedup 1.0000x reference)
//
#include <hip/hip_runtime.h>
#include <hip/hip_bf16.h>

// Problem constants: B=2, S=2048, D=1024, H=16, DH=64
#define SS 2048
#define DD 1024
#define GK 1024   // GEMM K = D
#define GM 4096   // GEMM M = B*S

// log2(e)/8 : folded into Q projection so attention softmax is exp2(s)
#define QSCALE 0.18033688011112042f

typedef __attribute__((ext_vector_type(8))) short short8;    // 8 bf16 = 4 VGPRs
typedef __attribute__((ext_vector_type(16))) float f32x16;   // 32x32 MFMA C/D
typedef __attribute__((ext_vector_type(2))) float f32x2;
typedef __attribute__((ext_vector_type(4))) int i32x4;

__device__ __forceinline__ short f2bf(float f) {
  union { __hip_bfloat16 h; short s; } u;
  u.h = __float2bfloat16(f);
  return u.s;
}

__device__ __forceinline__ short2 pk2bf(float a, float b) {
  union { __hip_bfloat162 h; short2 s; } u;
  u.h = __float22bfloat162_rn(float2{a, b});
  return u.s;
}

__device__ __forceinline__ int pk2bf_i(float a, float b) {
  union { __hip_bfloat162 h; int i; } u;
  u.h = __float22bfloat162_rn(float2{a, b});
  return u.i;
}

// async global->LDS, 16B per lane; LDS dest = wave-uniform base + lane*16
__device__ __forceinline__ void gld16(const void* g, void* l) {
  __builtin_amdgcn_global_load_lds(
      (const __attribute__((address_space(1))) void*)g,
      (__attribute__((address_space(3))) void*)l, 16, 0, 0);
}

// Tile swizzle: stored chunk c of row r holds source chunk c^(r&7)^((r>>3)&3).
// (r>>3)&3 term: the 4 rows sharing r&7 in a 32-row fragment read hit
// distinct bank groups (round-6 verified: SQ_LDS_BANK_CONFLICT -> 0).
// Works for 8-chunk (64-col) and 16-chunk (128-col) rows alike.
__device__ __forceinline__ int swz(int row, int col) {
  return (col ^ (row & 7) ^ ((row >> 3) & 3)) << 3;
}

// ---------------------------------------------------------------------------
// fp32 -> bf16 convert, weights only (q/k/v conversion fused into qkv_gemm)
// ---------------------------------------------------------------------------
struct CvtArgs {
  const float* s[4];
  short* d[4];
};

__global__ __launch_bounds__(256) void cvt_all(CvtArgs a) {
  const int y = blockIdx.y;
  const int i = blockIdx.x * 256 + threadIdx.x;  // 131072 chunks of 8
  const float4* sp = (const float4*)a.s[y];
  float4 u = sp[2 * i], v = sp[2 * i + 1];
  short8 o;
  short2 p0 = pk2bf(u.x, u.y), p1 = pk2bf(u.z, u.w);
  short2 p2 = pk2bf(v.x, v.y), p3 = pk2bf(v.z, v.w);
  o[0] = p0.x; o[1] = p0.y; o[2] = p1.x; o[3] = p1.y;
  o[4] = p2.x; o[5] = p2.y; o[6] = p3.x; o[7] = p3.y;
  ((short8*)a.d[y])[i] = o;
}

// ---------------------------------------------------------------------------
// Fused QKV projection GEMM. A = x (fp32, converted to bf16 during staging
// — kills the separate q/k/v cvt pass: ~50 MB HBM saved), B = W (bf16,
// async gld16). grid = 768 blocks, 3 blocks/CU, XCD-remapped.
// V^T epilogue transposes through LDS, coalesced 16B stores (m0&2047
// batch fix from round-4).
// ---------------------------------------------------------------------------
struct QkvArgs {
  const float* A[3];   // fp32 inputs q,k,v
  const short* W[3];
  const float* b[3];
  short* out[3];
};

__global__ __launch_bounds__(256, 3) void qkv_gemm(QkvArgs args) {
  // bijective flat-id remap: xcd = f&7 (hardware round-robin assumption)
  const int f = blockIdx.x + 32 * (blockIdx.y + 8 * blockIdx.z);
  const int xcd = f & 7, slot = f >> 3;   // slot in [0,96)
  const int z = slot >> 5;                // which projection (q/k/v)
  const int rem = slot & 31;
  const int m0 = (xcd * 4 + (rem & 3)) * 128;  // s
  const int n0 = (rem >> 2) * 128;             // feat

  const float* __restrict__ A = args.A[z];
  const short* __restrict__ W = args.W[z];
  const float* __restrict__ bias = args.b[z];
  short* __restrict__ Cout = args.out[z];

  const int tid = threadIdx.x;
  const int wave = tid >> 6, lane = tid & 63;
  const int l32 = lane & 31, half = lane >> 5;
  const int wrow = (wave >> 1) * 64;
  const int wcol = (wave & 1) * 64;
  const int lxor = (l32 & 7) ^ ((l32 >> 3) & 3);

  __shared__ short smem[16384];              // 32 KB: Am | Wm, reused as TT
  short (*Am)[64] = (short(*)[64])smem;          // [128][64] swizzled
  short (*Wm)[64] = (short(*)[64])(smem + 8192); // [128][64] swizzled

  f32x16 acc[2][2];
#pragma unroll
  for (int mb = 0; mb < 2; mb++)
#pragma unroll
    for (int nb = 0; nb < 2; nb++) acc[mb][nb] = (f32x16)0.f;

  for (int k0 = 0; k0 < GK; k0 += 64) {
    __syncthreads();
#pragma unroll
    for (int i = 0; i < 4; i++) {
      int f2 = wave * 256 + i * 64 + lane;
      int row = f2 >> 3, col = f2 & 7;
      int ksw = k0 + swz(row, col);
      // A: fp32 -> bf16 reg-staged (same RN rounding as the old cvt pass)
      const float* src = A + (size_t)(m0 + row) * GK + ksw;
      float4 u = *(const float4*)src;
      float4 v = *(const float4*)(src + 4);
      short8 o;
      short2 p0 = pk2bf(u.x, u.y), p1 = pk2bf(u.z, u.w);
      short2 p2 = pk2bf(v.x, v.y), p3 = pk2bf(v.z, v.w);
      o[0] = p0.x; o[1] = p0.y; o[2] = p1.x; o[3] = p1.y;
      o[4] = p2.x; o[5] = p2.y; o[6] = p3.x; o[7] = p3.y;
      *(short8*)((short*)Am + (size_t)f2 * 8) = o;
      // W: bf16 async global->LDS
      gld16(W + (size_t)(n0 + row) * GK + ksw,
            (short*)Wm + (size_t)(wave * 256 + i * 64) * 8);
    }
    __syncthreads();
#pragma unroll
    for (int c = 0; c < 4; c++) {
      const int sw = ((2 * c + half) ^ lxor) << 3;
      short8 af[2], bf[2];
#pragma unroll
      for (int mb = 0; mb < 2; mb++) {
        af[mb] = *(const short8*)(&Am[wrow + mb * 32 + l32][0] + sw);
        bf[mb] = *(const short8*)(&Wm[wcol + mb * 32 + l32][0] + sw);
      }
#pragma unroll
      for (int mb = 0; mb < 2; mb++)
#pragma unroll
        for (int nb = 0; nb < 2; nb++)
          acc[mb][nb] = __builtin_amdgcn_mfma_f32_32x32x16_bf16(
              af[mb], bf[nb], acc[mb][nb], 0, 0, 0);
    }
  }

  const int bb = m0 >> 11;

  if (z == 2) {
    // --- V^T epilogue: transpose via LDS, coalesced stores ---
    __syncthreads();  // all K-loop LDS reads done before overwrite
    short* TT = smem; // [128 feat][16 chunks of 8 s], chunk-XOR swizzled
#pragma unroll
    for (int nb = 0; nb < 2; nb++) {
      const int fl = wcol + nb * 32 + l32;   // feat_local 0..127
      const float bv = bias[n0 + fl];
#pragma unroll
      for (int mb = 0; mb < 2; mb++)
#pragma unroll
        for (int g = 0; g < 4; g++) {
          const int cs = (wrow >> 3) + mb * 4 + g;            // 0..15
          const int csw = cs ^ (fl & 7) ^ ((fl >> 3) & 3);
          short2 o0 = pk2bf(acc[mb][nb][4 * g + 0] + bv,
                            acc[mb][nb][4 * g + 1] + bv);
          short2 o1 = pk2bf(acc[mb][nb][4 * g + 2] + bv,
                            acc[mb][nb][4 * g + 3] + bv);
          short4 o4 = {o0.x, o0.y, o1.x, o1.y};
          *(short4*)&TT[fl * 128 + csw * 8 + 4 * half] = o4;
        }
    }
    __syncthreads();
    {
      const int fl = tid >> 1;                       // feat row 0..127
      const int h = (n0 + fl) >> 6, d = (n0 + fl) & 63;
      short* dst = Cout + ((size_t)(bb * 16 + h) * 64 + d) * 2048 +
                   (m0 & 2047) + (tid & 1) * 64;
#pragma unroll
      for (int j = 0; j < 8; j++) {
        const int c8 = (tid & 1) * 8 + j;
        const int csw = c8 ^ (fl & 7) ^ ((fl >> 3) & 3);
        *(short8*)(dst + j * 8) = *(const short8*)&TT[fl * 128 + csw * 8];
      }
    }
    return;
  }

  // --- q/k epilogue: n(lane)=feat, m(regs)=s. Coalesced along feat. ---
  const float sc = (z == 0) ? QSCALE : 1.0f;
#pragma unroll
  for (int nb = 0; nb < 2; nb++) {
    const int n = n0 + wcol + nb * 32 + l32;
    const float bv = bias[n];
    const int h = n >> 6, d = n & 63;
#pragma unroll
    for (int mb = 0; mb < 2; mb++) {
      const int mbase = m0 + wrow + mb * 32 + 4 * half;
#pragma unroll
      for (int g = 0; g < 4; g++)
#pragma unroll
        for (int r = 0; r < 4; r++) {
          const int s = (mbase + g * 8 + r) & 2047;
          Cout[((size_t)(bb * 16 + h) * 2048 + s) * 64 + d] =
              f2bf((acc[mb][nb][4 * g + r] + bv) * sc);
        }
    }
  }
}

// ---------------------------------------------------------------------------
// O-projection GEMM, BK=128: 16 MFMA/wave/iter, 16 barriers. LDS 48 KB,
// grid (32,16) = 512 = 2 blocks/CU. fp32 out, coalesced along feat.
// XCD remap: each XCD owns 4 m-panels x all 16 n-tiles: A 1MB + W 2MB.
// ---------------------------------------------------------------------------
__global__ __launch_bounds__(256) void gemm_o(
    const short* __restrict__ A, const short* __restrict__ W,
    const float* __restrict__ bias, float* __restrict__ Cout) {
  const int f = blockIdx.x + 32 * blockIdx.y;
  const int xcd = f & 7, slot = f >> 3;        // slot in [0,64)
  const int m0 = (xcd * 4 + (slot & 3)) * 128; // s
  const int n0 = (slot >> 2) * 64;             // feat

  const int tid = threadIdx.x;
  const int wave = tid >> 6, lane = tid & 63;
  const int l32 = lane & 31, half = lane >> 5;
  const int lxor = (l32 & 7) ^ ((l32 >> 3) & 3);

  __shared__ short Am[128][128];  // [s][k], swizzled (32 KB)
  __shared__ short Wm[64][128];   // [feat][k], swizzled (16 KB)

  f32x16 acc[2];
  acc[0] = (f32x16)0.f;
  acc[1] = (f32x16)0.f;

  for (int k0 = 0; k0 < GK; k0 += 128) {
    __syncthreads();
    // A: 128 rows x 16 chunks = 2048 chunks -> 8 per thread
#pragma unroll
    for (int i = 0; i < 8; i++) {
      int f2 = tid + i * 256;
      int row = f2 >> 4, col = f2 & 15;
      gld16(A + (size_t)(m0 + row) * GK + k0 + swz(row, col),
            (short*)Am + (size_t)(wave * 64 + i * 256) * 8);
    }
    // W: 64 rows x 16 chunks = 1024 chunks -> 4 per thread
#pragma unroll
    for (int i = 0; i < 4; i++) {
      int f2 = tid + i * 256;
      int row = f2 >> 4, col = f2 & 15;
      gld16(W + (size_t)(n0 + row) * GK + k0 + swz(row, col),
            (short*)Wm + (size_t)(wave * 64 + i * 256) * 8);
    }
    __syncthreads();
#pragma unroll
    for (int c = 0; c < 8; c++) {
      const int sw = ((2 * c + half) ^ lxor) << 3;
      short8 af = *(const short8*)(&Am[wave * 32 + l32][0] + sw);
      short8 bf[2];
#pragma unroll
      for (int nb = 0; nb < 2; nb++)
        bf[nb] = *(const short8*)(&Wm[nb * 32 + l32][0] + sw);
#pragma unroll
      for (int nb = 0; nb < 2; nb++)
        acc[nb] = __builtin_amdgcn_mfma_f32_32x32x16_bf16(
            af, bf[nb], acc[nb], 0, 0, 0);
    }
  }

  // n(lane)=feat -> coalesced scalar stores
#pragma unroll
  for (int nb = 0; nb < 2; nb++) {
    const int n = n0 + nb * 32 + l32;
    const float bv = bias[n];
    const int mbase = m0 + wave * 32 + 4 * half;
#pragma unroll
    for (int g = 0; g < 4; g++)
#pragma unroll
      for (int r = 0; r < 4; r++)
        Cout[(size_t)(mbase + g * 8 + r) * DD + n] = acc[nb][4 * g + r] + bv;
  }
}

// ---------------------------------------------------------------------------
// Flash attention — round-2 schedule restored verbatim (round-3/4's
// intra-wave reorder caused VGPR spills: WRITE_SIZE 15.4->28.7 MB scratch
// traffic, -24% perf; reverted). kt-split 8-wave blocks, in-register P via
// cvt_pk+permlane32_swap, setprio on MFMA clusters, XCD-aware remap.
// ---------------------------------------------------------------------------
__global__ __launch_bounds__(512, 4) void flash_mfma(
    const short* __restrict__ qh, const short* __restrict__ kh,
    const short* __restrict__ vt, short* __restrict__ ao) {
  // bijective remap: hardware flat id -> (bh, q-tile), 4 bh per XCD
  const int n = blockIdx.x + 16 * blockIdx.y;
  const int xcd = n & 7, slot = n >> 3;   // slot in [0,64)
  const int bh = xcd * 4 + (slot >> 4);
  const int q0 = (slot & 15) * 128;

  const int tid = threadIdx.x;
  const int w = tid >> 6, lane = tid & 63;
  const int grp = w >> 2;   // 0: even kt tiles, 1: odd kt tiles
  const int qw = w & 3;     // q sub-block (32 rows)
  const int l32 = lane & 31, half = lane >> 5;
  const int lxor = (l32 & 7) ^ ((l32 >> 3) & 3);

  __shared__ short Ks[4][64][64];   // 4 bufs x [kk][d], swizzled (32 KB)
  __shared__ short Vs[4][64][64];   // 4 bufs x [d][kk], swizzled (32 KB)

  // Q B-fragments from global: q = l32, chunk c: d = c*16 + half*8
  short8 qf[4];
#pragma unroll
  for (int c = 0; c < 4; c++)
    qf[c] = *(const short8*)(
        qh + ((size_t)bh * SS + q0 + qw * 32 + l32) * 64 + c * 16 + half * 8);

  f32x16 o[2];
  o[0] = (f32x16)0.f;
  o[1] = (f32x16)0.f;
  float l_part = 0.f;

  // Staging: thread owns chunk tid of each 64x64 tile (8 waves cover it).
  const int row = tid >> 3, col = tid & 7;
  const short* kb = kh + ((size_t)bh * SS + row) * 64 + swz(row, col);
  const short* vb = vt + ((size_t)bh * 64 + row) * SS + swz(row, col);
  short* kd = (short*)Ks + w * 512;   // wave-uniform LDS dest (+ buf*4096)
  short* vd = (short*)Vs + w * 512;

  // Prologue: tiles 0,1 -> bufs 0,1
  gld16(kb, kd);
  gld16(kb + 4096, kd + 4096);
  gld16(vb, vd);
  gld16(vb + 64, vd + 4096);
  const short* kp = kb + 8192;  // tile 2 (advances 2 tiles/phase)
  const short* vp = vb + 128;
  __syncthreads();

  auto phase = [&](const int bufbase, const bool pf) {
    if (pf) {  // prefetch next tile pair into the other buffer pair
      const int pb = bufbase ^ 2;
      gld16(kp, kd + pb * 4096);
      gld16(kp + 4096, kd + (pb + 1) * 4096);
      gld16(vp, vd + pb * 4096);
      gld16(vp + 64, vd + (pb + 1) * 4096);
      kp += 8192;
      vp += 128;
    }
    const int b = bufbase + grp;

    // S^T = K · Q^T : m = kk (2 blocks), n = q
    f32x16 s[2];
    s[0] = (f32x16)0.f;
    s[1] = (f32x16)0.f;
    __builtin_amdgcn_s_setprio(1);
#pragma unroll
    for (int c = 0; c < 4; c++) {
      const int sw = ((2 * c + half) ^ lxor) << 3;
      short8 kf[2];
#pragma unroll
      for (int mb = 0; mb < 2; mb++)
        kf[mb] = *(const short8*)(&Ks[b][mb * 32 + l32][0] + sw);
#pragma unroll
      for (int mb = 0; mb < 2; mb++)
        s[mb] = __builtin_amdgcn_mfma_f32_32x32x16_bf16(
            kf[mb], qf[c], s[mb], 0, 0, 0);
    }
    __builtin_amdgcn_s_setprio(0);

    // p = exp2(s)
#pragma unroll
    for (int mb = 0; mb < 2; mb++)
#pragma unroll
      for (int r = 0; r < 16; r++)
        s[mb][r] = __builtin_amdgcn_exp2f(s[mb][r]);

    // per-lane partial l via packed pairwise tree (v_pk_add_f32)
    {
      f32x2 t[8];
#pragma unroll
      for (int r = 0; r < 8; r++)
        t[r] = f32x2{s[0][2 * r], s[0][2 * r + 1]} +
               f32x2{s[1][2 * r], s[1][2 * r + 1]};
#pragma unroll
      for (int st = 4; st > 0; st >>= 1)
#pragma unroll
        for (int r = 0; r < st; r++) t[r] += t[r + st];
      l_part += t[0].x + t[0].y;
    }

    // P -> bf16 PV B-fragments entirely in registers.
    // Lane (l32,h) owns P rows rem = 8g+4h+{0..3} (regs 4g..4g+3) of each
    // 32-row block mb. Fragment for chunk c needs rem = 8*gsel+{0..7},
    // gsel = 2*(c&1)+half: lower 4 from the h'=0 lane, upper 4 from the
    // h'=1 lane. permlane32_swap(a,b) = {a.lo|b.lo, a.hi|b.hi} per half,
    // so swap(u[2cc], u[2cc+1]) yields both needed dwords at once.
    short8 pfrag[4];
#pragma unroll
    for (int mb = 0; mb < 2; mb++) {
      int u0[4], u1[4];
#pragma unroll
      for (int g = 0; g < 4; g++) {
        u0[g] = pk2bf_i(s[mb][4 * g + 0], s[mb][4 * g + 1]);
        u1[g] = pk2bf_i(s[mb][4 * g + 2], s[mb][4 * g + 3]);
      }
#pragma unroll
      for (int cc = 0; cc < 2; cc++) {
        auto r0 = __builtin_amdgcn_permlane32_swap(u0[2 * cc], u0[2 * cc + 1],
                                                   false, false);
        auto r1 = __builtin_amdgcn_permlane32_swap(u1[2 * cc], u1[2 * cc + 1],
                                                   false, false);
        union { i32x4 i; short8 s8; } pu;
        pu.i = i32x4{(int)r0[0], (int)r1[0], (int)r0[1], (int)r1[1]};
        pfrag[2 * mb + cc] = pu.s8;
      }
    }

    // O^T += V^T · P^T : m = d (2 blocks), n = q, k = kk
    __builtin_amdgcn_s_setprio(1);
#pragma unroll
    for (int c = 0; c < 4; c++) {
      const int sw = ((2 * c + half) ^ lxor) << 3;
      short8 vf[2];
#pragma unroll
      for (int mb = 0; mb < 2; mb++)
        vf[mb] = *(const short8*)(&Vs[b][mb * 32 + l32][0] + sw);
      short8 pf2 = pfrag[c];
#pragma unroll
      for (int mb = 0; mb < 2; mb++)
        o[mb] = __builtin_amdgcn_mfma_f32_32x32x16_bf16(
            vf[mb], pf2, o[mb], 0, 0, 0);
    }
    __builtin_amdgcn_s_setprio(0);

    __syncthreads();  // drains prefetch + guards buffer reuse
  };

#pragma unroll 1
  for (int p2 = 0; p2 < 8; p2++) {
    phase(0, true);       // tiles 4*p2, 4*p2+1 (bufs 0,1); stage bufs 2,3
    phase(2, p2 != 7);    // tiles 4*p2+2,+3  (bufs 2,3); stage bufs 0,1
  }

  // Epilogue: merge group-1 partials into group-0 via LDS, then store.
  float* fb = (float*)Ks;  // 32*256 f32 = 32 KB
  float* lb = (float*)Vs;
  if (grp == 1) {
#pragma unroll
    for (int mb = 0; mb < 2; mb++)
#pragma unroll
      for (int r = 0; r < 16; r++)
        fb[(mb * 16 + r) * 256 + qw * 64 + lane] = o[mb][r];
    lb[qw * 64 + lane] = l_part;
  }
  __syncthreads();
  if (grp == 0) {
#pragma unroll
    for (int mb = 0; mb < 2; mb++)
#pragma unroll
      for (int r = 0; r < 16; r++)
        o[mb][r] += fb[(mb * 16 + r) * 256 + qw * 64 + lane];
    l_part += lb[qw * 64 + lane];

    const float l_tot = l_part + __shfl_xor(l_part, 32);
    const float inv = 1.0f / l_tot;
    const int b_ = bh >> 4, h = bh & 15;
    const int q = q0 + qw * 32 + l32;
#pragma unroll
    for (int mb = 0; mb < 2; mb++)
#pragma unroll
      for (int g = 0; g < 4; g++) {
        const int d = mb * 32 + g * 8 + half * 4;
        short2 o0 = pk2bf(o[mb][4 * g + 0] * inv, o[mb][4 * g + 1] * inv);
        short2 o1 = pk2bf(o[mb][4 * g + 2] * inv, o[mb][4 * g + 3] * inv);
        short4 ok = {o0.x, o0.y, o1.x, o1.y};
        *(short4*)&ao[((size_t)b_ * SS + q) * DD + h * 64 + d] = ok;
      }
  }
}

// ---------------------------------------------------------------------------
extern "C" void kernel_launch(void* const* d_in, const int* in_sizes, int n_in,
                              void* d_out, int out_size, void* d_ws,
                              size_t ws_size, hipStream_t stream) {
  const float* q = (const float*)d_in[0];
  const float* k = (const float*)d_in[1];
  const float* v = (const float*)d_in[2];
  const float* Wq = (const float*)d_in[3];
  const float* bq = (const float*)d_in[4];
  const float* Wk = (const float*)d_in[5];
  const float* bk = (const float*)d_in[6];
  const float* Wv = (const float*)d_in[7];
  const float* bv = (const float*)d_in[8];
  const float* Wo = (const float*)d_in[9];
  const float* bo = (const float*)d_in[10];
  float* out = (float*)d_out;

  const size_t MEG = 1024 * 1024;
  short* wsb = (short*)d_ws;
  short* Wqb = wsb + 0 * MEG;
  short* Wkb = wsb + 1 * MEG;
  short* Wvb = wsb + 2 * MEG;
  short* Wob = wsb + 3 * MEG;
  short* qhp = wsb + 16 * MEG;  // [B*H][S][DH] (pre-scaled by log2e/8)
  short* khp = wsb + 20 * MEG;  // [B*H][S][DH]
  short* vtp = wsb + 24 * MEG;  // [B*H][DH][S]
  short* aop = wsb + 28 * MEG;  // [B,S,D]

  CvtArgs ca;
  ca.s[0] = Wq; ca.d[0] = Wqb;
  ca.s[1] = Wk; ca.d[1] = Wkb;
  ca.s[2] = Wv; ca.d[2] = Wvb;
  ca.s[3] = Wo; ca.d[3] = Wob;
  cvt_all<<<dim3(512, 4), 256, 0, stream>>>(ca);

  QkvArgs qa;
  qa.A[0] = q; qa.W[0] = Wqb; qa.b[0] = bq; qa.out[0] = qhp;
  qa.A[1] = k; qa.W[1] = Wkb; qa.b[1] = bk; qa.out[1] = khp;
  qa.A[2] = v; qa.W[2] = Wvb; qa.b[2] = bv; qa.out[2] = vtp;
  qkv_gemm<<<dim3(GM / 128, DD / 128, 3), 256, 0, stream>>>(qa);

  flash_mfma<<<dim3(SS / 128, 32), 512, 0, stream>>>(qhp, khp, vtp, aop);

  gemm_o<<<dim3(GM / 128, DD / 64), 256, 0, stream>>>(aop, Wob, bo, out);
}

// Round 6
// 214.554 us; speedup vs baseline: 1.0893x; 1.0893x over previous
//
#include <hip/hip_runtime.h>
#include <hip/hip_bf16.h>

// Problem constants: B=2, S=2048, D=1024, H=16, DH=64
#define SS 2048
#define DD 1024
#define GK 1024   // GEMM K = D
#define GM 4096   // GEMM M = B*S

// log2(e)/8 : folded into Q projection so attention softmax is exp2(s)
#define QSCALE 0.18033688011112042f

typedef __attribute__((ext_vector_type(8))) short short8;    // 8 bf16 = 4 VGPRs
typedef __attribute__((ext_vector_type(16))) float f32x16;   // 32x32 MFMA C/D
typedef __attribute__((ext_vector_type(2))) float f32x2;
typedef __attribute__((ext_vector_type(4))) int i32x4;

__device__ __forceinline__ short f2bf(float f) {
  union { __hip_bfloat16 h; short s; } u;
  u.h = __float2bfloat16(f);
  return u.s;
}

__device__ __forceinline__ short2 pk2bf(float a, float b) {
  union { __hip_bfloat162 h; short2 s; } u;
  u.h = __float22bfloat162_rn(float2{a, b});
  return u.s;
}

__device__ __forceinline__ int pk2bf_i(float a, float b) {
  union { __hip_bfloat162 h; int i; } u;
  u.h = __float22bfloat162_rn(float2{a, b});
  return u.i;
}

// async global->LDS, 16B per lane; LDS dest = wave-uniform base + lane*16
__device__ __forceinline__ void gld16(const void* g, void* l) {
  __builtin_amdgcn_global_load_lds(
      (const __attribute__((address_space(1))) void*)g,
      (__attribute__((address_space(3))) void*)l, 16, 0, 0);
}

// Tile swizzle: stored chunk c of row r holds source chunk c^(r&7)^((r>>3)&3).
__device__ __forceinline__ int swz(int row, int col) {
  return (col ^ (row & 7) ^ ((row >> 3) & 3)) << 3;
}

// ---------------------------------------------------------------------------
// fp32 -> bf16 convert, weights only (q/k/v conversion fused into qkv_gemm)
// ---------------------------------------------------------------------------
struct CvtArgs {
  const float* s[4];
  short* d[4];
};

__global__ __launch_bounds__(256) void cvt_all(CvtArgs a) {
  const int y = blockIdx.y;
  const int i = blockIdx.x * 256 + threadIdx.x;  // 131072 chunks of 8
  const float4* sp = (const float4*)a.s[y];
  float4 u = sp[2 * i], v = sp[2 * i + 1];
  short8 o;
  short2 p0 = pk2bf(u.x, u.y), p1 = pk2bf(u.z, u.w);
  short2 p2 = pk2bf(v.x, v.y), p3 = pk2bf(v.z, v.w);
  o[0] = p0.x; o[1] = p0.y; o[2] = p1.x; o[3] = p1.y;
  o[4] = p2.x; o[5] = p2.y; o[6] = p3.x; o[7] = p3.y;
  ((short8*)a.d[y])[i] = o;
}

// ---------------------------------------------------------------------------
// Fused QKV projection GEMM. A = x (fp32 -> bf16 during staging), B = W
// (bf16, async gld16). Round-6: A loads are PIPELINED one k-step ahead —
// round-5's sync loads put HBM latency on the critical path every k-step
// (VALUBusy 9.9%, qkv 70us). Now: iteration k converts+writes the regs
// loaded at k-1, then issues k+1's loads; latency hides under the 16-MFMA
// compute phase. grid = 768 blocks, 3 blocks/CU, XCD-remapped.
// ---------------------------------------------------------------------------
struct QkvArgs {
  const float* A[3];   // fp32 inputs q,k,v
  const short* W[3];
  const float* b[3];
  short* out[3];
};

__global__ __launch_bounds__(256, 3) void qkv_gemm(QkvArgs args) {
  // bijective flat-id remap: xcd = f&7 (hardware round-robin assumption)
  const int f = blockIdx.x + 32 * (blockIdx.y + 8 * blockIdx.z);
  const int xcd = f & 7, slot = f >> 3;   // slot in [0,96)
  const int z = slot >> 5;                // which projection (q/k/v)
  const int rem = slot & 31;
  const int m0 = (xcd * 4 + (rem & 3)) * 128;  // s
  const int n0 = (rem >> 2) * 128;             // feat

  const float* __restrict__ A = args.A[z];
  const short* __restrict__ W = args.W[z];
  const float* __restrict__ bias = args.b[z];
  short* __restrict__ Cout = args.out[z];

  const int tid = threadIdx.x;
  const int wave = tid >> 6, lane = tid & 63;
  const int l32 = lane & 31, half = lane >> 5;
  const int wrow = (wave >> 1) * 64;
  const int wcol = (wave & 1) * 64;
  const int lxor = (l32 & 7) ^ ((l32 >> 3) & 3);

  __shared__ short smem[16384];              // 32 KB: Am | Wm, reused as TT
  short (*Am)[64] = (short(*)[64])smem;          // [128][64] swizzled
  short (*Wm)[64] = (short(*)[64])(smem + 8192); // [128][64] swizzled

  f32x16 acc[2][2];
#pragma unroll
  for (int mb = 0; mb < 2; mb++)
#pragma unroll
    for (int nb = 0; nb < 2; nb++) acc[mb][nb] = (f32x16)0.f;

  // Per-thread A-staging geometry (constant across k): 4 chunks
  int arow[4], acolsw[4];
#pragma unroll
  for (int i = 0; i < 4; i++) {
    int f2 = wave * 256 + i * 64 + lane;
    arow[i] = f2 >> 3;
    acolsw[i] = swz(arow[i], f2 & 7);
  }

  // Prologue: load A chunks for k0 = 0
  float4 au[4], av[4];
#pragma unroll
  for (int i = 0; i < 4; i++) {
    const float* src = A + (size_t)(m0 + arow[i]) * GK + acolsw[i];
    au[i] = *(const float4*)src;
    av[i] = *(const float4*)(src + 4);
  }

  for (int k0 = 0; k0 < GK; k0 += 64) {
    __syncthreads();
#pragma unroll
    for (int i = 0; i < 4; i++) {
      int f2 = wave * 256 + i * 64 + lane;
      // A: convert the prefetched regs -> LDS (RN, same as old cvt pass)
      short8 o;
      short2 p0 = pk2bf(au[i].x, au[i].y), p1 = pk2bf(au[i].z, au[i].w);
      short2 p2 = pk2bf(av[i].x, av[i].y), p3 = pk2bf(av[i].z, av[i].w);
      o[0] = p0.x; o[1] = p0.y; o[2] = p1.x; o[3] = p1.y;
      o[4] = p2.x; o[5] = p2.y; o[6] = p3.x; o[7] = p3.y;
      *(short8*)((short*)Am + (size_t)f2 * 8) = o;
      // W: bf16 async global->LDS
      gld16(W + (size_t)(n0 + arow[i]) * GK + k0 + acolsw[i],
            (short*)Wm + (size_t)(wave * 256 + i * 64) * 8);
    }
    // Issue next k-step's A loads; in flight across the compute phase.
    if (k0 + 64 < GK) {
#pragma unroll
      for (int i = 0; i < 4; i++) {
        const float* src =
            A + (size_t)(m0 + arow[i]) * GK + (k0 + 64) + acolsw[i];
        au[i] = *(const float4*)src;
        av[i] = *(const float4*)(src + 4);
      }
    }
    __syncthreads();
#pragma unroll
    for (int c = 0; c < 4; c++) {
      const int sw = ((2 * c + half) ^ lxor) << 3;
      short8 af[2], bf[2];
#pragma unroll
      for (int mb = 0; mb < 2; mb++) {
        af[mb] = *(const short8*)(&Am[wrow + mb * 32 + l32][0] + sw);
        bf[mb] = *(const short8*)(&Wm[wcol + mb * 32 + l32][0] + sw);
      }
#pragma unroll
      for (int mb = 0; mb < 2; mb++)
#pragma unroll
        for (int nb = 0; nb < 2; nb++)
          acc[mb][nb] = __builtin_amdgcn_mfma_f32_32x32x16_bf16(
              af[mb], bf[nb], acc[mb][nb], 0, 0, 0);
    }
  }

  const int bb = m0 >> 11;

  if (z == 2) {
    // --- V^T epilogue: transpose via LDS, coalesced stores ---
    __syncthreads();  // all K-loop LDS reads done before overwrite
    short* TT = smem; // [128 feat][16 chunks of 8 s], chunk-XOR swizzled
#pragma unroll
    for (int nb = 0; nb < 2; nb++) {
      const int fl = wcol + nb * 32 + l32;   // feat_local 0..127
      const float bv = bias[n0 + fl];
#pragma unroll
      for (int mb = 0; mb < 2; mb++)
#pragma unroll
        for (int g = 0; g < 4; g++) {
          const int cs = (wrow >> 3) + mb * 4 + g;            // 0..15
          const int csw = cs ^ (fl & 7) ^ ((fl >> 3) & 3);
          short2 o0 = pk2bf(acc[mb][nb][4 * g + 0] + bv,
                            acc[mb][nb][4 * g + 1] + bv);
          short2 o1 = pk2bf(acc[mb][nb][4 * g + 2] + bv,
                            acc[mb][nb][4 * g + 3] + bv);
          short4 o4 = {o0.x, o0.y, o1.x, o1.y};
          *(short4*)&TT[fl * 128 + csw * 8 + 4 * half] = o4;
        }
    }
    __syncthreads();
    {
      const int fl = tid >> 1;                       // feat row 0..127
      const int h = (n0 + fl) >> 6, d = (n0 + fl) & 63;
      short* dst = Cout + ((size_t)(bb * 16 + h) * 64 + d) * 2048 +
                   (m0 & 2047) + (tid & 1) * 64;
#pragma unroll
      for (int j = 0; j < 8; j++) {
        const int c8 = (tid & 1) * 8 + j;
        const int csw = c8 ^ (fl & 7) ^ ((fl >> 3) & 3);
        *(short8*)(dst + j * 8) = *(const short8*)&TT[fl * 128 + csw * 8];
      }
    }
    return;
  }

  // --- q/k epilogue: n(lane)=feat, m(regs)=s. Coalesced along feat. ---
  const float sc = (z == 0) ? QSCALE : 1.0f;
#pragma unroll
  for (int nb = 0; nb < 2; nb++) {
    const int n = n0 + wcol + nb * 32 + l32;
    const float bv = bias[n];
    const int h = n >> 6, d = n & 63;
#pragma unroll
    for (int mb = 0; mb < 2; mb++) {
      const int mbase = m0 + wrow + mb * 32 + 4 * half;
#pragma unroll
      for (int g = 0; g < 4; g++)
#pragma unroll
        for (int r = 0; r < 4; r++) {
          const int s = (mbase + g * 8 + r) & 2047;
          Cout[((size_t)(bb * 16 + h) * 2048 + s) * 64 + d] =
              f2bf((acc[mb][nb][4 * g + r] + bv) * sc);
        }
    }
  }
}

// ---------------------------------------------------------------------------
// O-projection GEMM, BK=128: 16 MFMA/wave/iter, 16 barriers. LDS 48 KB,
// grid (32,16) = 512 = 2 blocks/CU. fp32 out, coalesced along feat.
// XCD remap: each XCD owns 4 m-panels x all 16 n-tiles: A 1MB + W 2MB.
// ---------------------------------------------------------------------------
__global__ __launch_bounds__(256) void gemm_o(
    const short* __restrict__ A, const short* __restrict__ W,
    const float* __restrict__ bias, float* __restrict__ Cout) {
  const int f = blockIdx.x + 32 * blockIdx.y;
  const int xcd = f & 7, slot = f >> 3;        // slot in [0,64)
  const int m0 = (xcd * 4 + (slot & 3)) * 128; // s
  const int n0 = (slot >> 2) * 64;             // feat

  const int tid = threadIdx.x;
  const int wave = tid >> 6, lane = tid & 63;
  const int l32 = lane & 31, half = lane >> 5;
  const int lxor = (l32 & 7) ^ ((l32 >> 3) & 3);

  __shared__ short Am[128][128];  // [s][k], swizzled (32 KB)
  __shared__ short Wm[64][128];   // [feat][k], swizzled (16 KB)

  f32x16 acc[2];
  acc[0] = (f32x16)0.f;
  acc[1] = (f32x16)0.f;

  for (int k0 = 0; k0 < GK; k0 += 128) {
    __syncthreads();
    // A: 128 rows x 16 chunks = 2048 chunks -> 8 per thread
#pragma unroll
    for (int i = 0; i < 8; i++) {
      int f2 = tid + i * 256;
      int row = f2 >> 4, col = f2 & 15;
      gld16(A + (size_t)(m0 + row) * GK + k0 + swz(row, col),
            (short*)Am + (size_t)(wave * 64 + i * 256) * 8);
    }
    // W: 64 rows x 16 chunks = 1024 chunks -> 4 per thread
#pragma unroll
    for (int i = 0; i < 4; i++) {
      int f2 = tid + i * 256;
      int row = f2 >> 4, col = f2 & 15;
      gld16(W + (size_t)(n0 + row) * GK + k0 + swz(row, col),
            (short*)Wm + (size_t)(wave * 64 + i * 256) * 8);
    }
    __syncthreads();
#pragma unroll
    for (int c = 0; c < 8; c++) {
      const int sw = ((2 * c + half) ^ lxor) << 3;
      short8 af = *(const short8*)(&Am[wave * 32 + l32][0] + sw);
      short8 bf[2];
#pragma unroll
      for (int nb = 0; nb < 2; nb++)
        bf[nb] = *(const short8*)(&Wm[nb * 32 + l32][0] + sw);
#pragma unroll
      for (int nb = 0; nb < 2; nb++)
        acc[nb] = __builtin_amdgcn_mfma_f32_32x32x16_bf16(
            af, bf[nb], acc[nb], 0, 0, 0);
    }
  }

  // n(lane)=feat -> coalesced scalar stores
#pragma unroll
  for (int nb = 0; nb < 2; nb++) {
    const int n = n0 + nb * 32 + l32;
    const float bv = bias[n];
    const int mbase = m0 + wave * 32 + 4 * half;
#pragma unroll
    for (int g = 0; g < 4; g++)
#pragma unroll
      for (int r = 0; r < 4; r++)
        Cout[(size_t)(mbase + g * 8 + r) * DD + n] = acc[nb][4 * g + r] + bv;
  }
}

// ---------------------------------------------------------------------------
// Flash attention — round-2 schedule (known-good, 52.8us): kt-split 8-wave
// blocks, in-register P via cvt_pk+permlane32_swap, setprio on MFMA
// clusters, XCD-aware remap.
// ---------------------------------------------------------------------------
__global__ __launch_bounds__(512, 4) void flash_mfma(
    const short* __restrict__ qh, const short* __restrict__ kh,
    const short* __restrict__ vt, short* __restrict__ ao) {
  // bijective remap: hardware flat id -> (bh, q-tile), 4 bh per XCD
  const int n = blockIdx.x + 16 * blockIdx.y;
  const int xcd = n & 7, slot = n >> 3;   // slot in [0,64)
  const int bh = xcd * 4 + (slot >> 4);
  const int q0 = (slot & 15) * 128;

  const int tid = threadIdx.x;
  const int w = tid >> 6, lane = tid & 63;
  const int grp = w >> 2;   // 0: even kt tiles, 1: odd kt tiles
  const int qw = w & 3;     // q sub-block (32 rows)
  const int l32 = lane & 31, half = lane >> 5;
  const int lxor = (l32 & 7) ^ ((l32 >> 3) & 3);

  __shared__ short Ks[4][64][64];   // 4 bufs x [kk][d], swizzled (32 KB)
  __shared__ short Vs[4][64][64];   // 4 bufs x [d][kk], swizzled (32 KB)

  // Q B-fragments from global: q = l32, chunk c: d = c*16 + half*8
  short8 qf[4];
#pragma unroll
  for (int c = 0; c < 4; c++)
    qf[c] = *(const short8*)(
        qh + ((size_t)bh * SS + q0 + qw * 32 + l32) * 64 + c * 16 + half * 8);

  f32x16 o[2];
  o[0] = (f32x16)0.f;
  o[1] = (f32x16)0.f;
  float l_part = 0.f;

  // Staging: thread owns chunk tid of each 64x64 tile (8 waves cover it).
  const int row = tid >> 3, col = tid & 7;
  const short* kb = kh + ((size_t)bh * SS + row) * 64 + swz(row, col);
  const short* vb = vt + ((size_t)bh * 64 + row) * SS + swz(row, col);
  short* kd = (short*)Ks + w * 512;   // wave-uniform LDS dest (+ buf*4096)
  short* vd = (short*)Vs + w * 512;

  // Prologue: tiles 0,1 -> bufs 0,1
  gld16(kb, kd);
  gld16(kb + 4096, kd + 4096);
  gld16(vb, vd);
  gld16(vb + 64, vd + 4096);
  const short* kp = kb + 8192;  // tile 2 (advances 2 tiles/phase)
  const short* vp = vb + 128;
  __syncthreads();

  auto phase = [&](const int bufbase, const bool pf) {
    if (pf) {  // prefetch next tile pair into the other buffer pair
      const int pb = bufbase ^ 2;
      gld16(kp, kd + pb * 4096);
      gld16(kp + 4096, kd + (pb + 1) * 4096);
      gld16(vp, vd + pb * 4096);
      gld16(vp + 64, vd + (pb + 1) * 4096);
      kp += 8192;
      vp += 128;
    }
    const int b = bufbase + grp;

    // S^T = K · Q^T : m = kk (2 blocks), n = q
    f32x16 s[2];
    s[0] = (f32x16)0.f;
    s[1] = (f32x16)0.f;
    __builtin_amdgcn_s_setprio(1);
#pragma unroll
    for (int c = 0; c < 4; c++) {
      const int sw = ((2 * c + half) ^ lxor) << 3;
      short8 kf[2];
#pragma unroll
      for (int mb = 0; mb < 2; mb++)
        kf[mb] = *(const short8*)(&Ks[b][mb * 32 + l32][0] + sw);
#pragma unroll
      for (int mb = 0; mb < 2; mb++)
        s[mb] = __builtin_amdgcn_mfma_f32_32x32x16_bf16(
            kf[mb], qf[c], s[mb], 0, 0, 0);
    }
    __builtin_amdgcn_s_setprio(0);

    // p = exp2(s)
#pragma unroll
    for (int mb = 0; mb < 2; mb++)
#pragma unroll
      for (int r = 0; r < 16; r++)
        s[mb][r] = __builtin_amdgcn_exp2f(s[mb][r]);

    // per-lane partial l via packed pairwise tree (v_pk_add_f32)
    {
      f32x2 t[8];
#pragma unroll
      for (int r = 0; r < 8; r++)
        t[r] = f32x2{s[0][2 * r], s[0][2 * r + 1]} +
               f32x2{s[1][2 * r], s[1][2 * r + 1]};
#pragma unroll
      for (int st = 4; st > 0; st >>= 1)
#pragma unroll
        for (int r = 0; r < st; r++) t[r] += t[r + st];
      l_part += t[0].x + t[0].y;
    }

    // P -> bf16 PV B-fragments entirely in registers.
    short8 pfrag[4];
#pragma unroll
    for (int mb = 0; mb < 2; mb++) {
      int u0[4], u1[4];
#pragma unroll
      for (int g = 0; g < 4; g++) {
        u0[g] = pk2bf_i(s[mb][4 * g + 0], s[mb][4 * g + 1]);
        u1[g] = pk2bf_i(s[mb][4 * g + 2], s[mb][4 * g + 3]);
      }
#pragma unroll
      for (int cc = 0; cc < 2; cc++) {
        auto r0 = __builtin_amdgcn_permlane32_swap(u0[2 * cc], u0[2 * cc + 1],
                                                   false, false);
        auto r1 = __builtin_amdgcn_permlane32_swap(u1[2 * cc], u1[2 * cc + 1],
                                                   false, false);
        union { i32x4 i; short8 s8; } pu;
        pu.i = i32x4{(int)r0[0], (int)r1[0], (int)r0[1], (int)r1[1]};
        pfrag[2 * mb + cc] = pu.s8;
      }
    }

    // O^T += V^T · P^T : m = d (2 blocks), n = q, k = kk
    __builtin_amdgcn_s_setprio(1);
#pragma unroll
    for (int c = 0; c < 4; c++) {
      const int sw = ((2 * c + half) ^ lxor) << 3;
      short8 vf[2];
#pragma unroll
      for (int mb = 0; mb < 2; mb++)
        vf[mb] = *(const short8*)(&Vs[b][mb * 32 + l32][0] + sw);
      short8 pf2 = pfrag[c];
#pragma unroll
      for (int mb = 0; mb < 2; mb++)
        o[mb] = __builtin_amdgcn_mfma_f32_32x32x16_bf16(
            vf[mb], pf2, o[mb], 0, 0, 0);
    }
    __builtin_amdgcn_s_setprio(0);

    __syncthreads();  // drains prefetch + guards buffer reuse
  };

#pragma unroll 1
  for (int p2 = 0; p2 < 8; p2++) {
    phase(0, true);       // tiles 4*p2, 4*p2+1 (bufs 0,1); stage bufs 2,3
    phase(2, p2 != 7);    // tiles 4*p2+2,+3  (bufs 2,3); stage bufs 0,1
  }

  // Epilogue: merge group-1 partials into group-0 via LDS, then store.
  float* fb = (float*)Ks;  // 32*256 f32 = 32 KB
  float* lb = (float*)Vs;
  if (grp == 1) {
#pragma unroll
    for (int mb = 0; mb < 2; mb++)
#pragma unroll
      for (int r = 0; r < 16; r++)
        fb[(mb * 16 + r) * 256 + qw * 64 + lane] = o[mb][r];
    lb[qw * 64 + lane] = l_part;
  }
  __syncthreads();
  if (grp == 0) {
#pragma unroll
    for (int mb = 0; mb < 2; mb++)
#pragma unroll
      for (int r = 0; r < 16; r++)
        o[mb][r] += fb[(mb * 16 + r) * 256 + qw * 64 + lane];
    l_part += lb[qw * 64 + lane];

    const float l_tot = l_part + __shfl_xor(l_part, 32);
    const float inv = 1.0f / l_tot;
    const int b_ = bh >> 4, h = bh & 15;
    const int q = q0 + qw * 32 + l32;
#pragma unroll
    for (int mb = 0; mb < 2; mb++)
#pragma unroll
      for (int g = 0; g < 4; g++) {
        const int d = mb * 32 + g * 8 + half * 4;
        short2 o0 = pk2bf(o[mb][4 * g + 0] * inv, o[mb][4 * g + 1] * inv);
        short2 o1 = pk2bf(o[mb][4 * g + 2] * inv, o[mb][4 * g + 3] * inv);
        short4 ok = {o0.x, o0.y, o1.x, o1.y};
        *(short4*)&ao[((size_t)b_ * SS + q) * DD + h * 64 + d] = ok;
      }
  }
}

// ---------------------------------------------------------------------------
extern "C" void kernel_launch(void* const* d_in, const int* in_sizes, int n_in,
                              void* d_out, int out_size, void* d_ws,
                              size_t ws_size, hipStream_t stream) {
  const float* q = (const float*)d_in[0];
  const float* k = (const float*)d_in[1];
  const float* v = (const float*)d_in[2];
  const float* Wq = (const float*)d_in[3];
  const float* bq = (const float*)d_in[4];
  const float* Wk = (const float*)d_in[5];
  const float* bk = (const float*)d_in[6];
  const float* Wv = (const float*)d_in[7];
  const float* bv = (const float*)d_in[8];
  const float* Wo = (const float*)d_in[9];
  const float* bo = (const float*)d_in[10];
  float* out = (float*)d_out;

  const size_t MEG = 1024 * 1024;
  short* wsb = (short*)d_ws;
  short* Wqb = wsb + 0 * MEG;
  short* Wkb = wsb + 1 * MEG;
  short* Wvb = wsb + 2 * MEG;
  short* Wob = wsb + 3 * MEG;
  short* qhp = wsb + 16 * MEG;  // [B*H][S][DH] (pre-scaled by log2e/8)
  short* khp = wsb + 20 * MEG;  // [B*H][S][DH]
  short* vtp = wsb + 24 * MEG;  // [B*H][DH][S]
  short* aop = wsb + 28 * MEG;  // [B,S,D]

  CvtArgs ca;
  ca.s[0] = Wq; ca.d[0] = Wqb;
  ca.s[1] = Wk; ca.d[1] = Wkb;
  ca.s[2] = Wv; ca.d[2] = Wvb;
  ca.s[3] = Wo; ca.d[3] = Wob;
  cvt_all<<<dim3(512, 4), 256, 0, stream>>>(ca);

  QkvArgs qa;
  qa.A[0] = q; qa.W[0] = Wqb; qa.b[0] = bq; qa.out[0] = qhp;
  qa.A[1] = k; qa.W[1] = Wkb; qa.b[1] = bk; qa.out[1] = khp;
  qa.A[2] = v; qa.W[2] = Wvb; qa.b[2] = bv; qa.out[2] = vtp;
  qkv_gemm<<<dim3(GM / 128, DD / 128, 3), 256, 0, stream>>>(qa);

  flash_mfma<<<dim3(SS / 128, 32), 512, 0, stream>>>(qhp, khp, vtp, aop);

  gemm_o<<<dim3(GM / 128, DD / 64), 256, 0, stream>>>(aop, Wob, bo, out);
}